// Round 5
// baseline (488.087 us; speedup 1.0000x reference)
//
#include <hip/hip_runtime.h>

#define NN 100000   // nodes
#define NE 800000   // edges  (NE % 256 == 0)
#define NG 256      // graphs
#define CH 96       // in/hidden channels
#define OC 16       // out channels
#define NBLK 391    // ceil(NN/256)
#define TM 128      // gemm node tile

// ---------------- CSR build ----------------
__global__ __launch_bounds__(256) void k_hist(const int* __restrict__ dst,
                                              int* __restrict__ cnt,
                                              int* __restrict__ slot) {
    int e = blockIdx.x * 256 + threadIdx.x;
    slot[e] = atomicAdd(&cnt[dst[e]], 1);
}

__global__ __launch_bounds__(256) void k_scan1(const int* __restrict__ cnt,
                                               int* __restrict__ off,
                                               int* __restrict__ bsum) {
    __shared__ int sh[256];
    int t = threadIdx.x;
    int i = blockIdx.x * 256 + t;
    int v = (i < NN) ? cnt[i] : 0;
    sh[t] = v;
    __syncthreads();
    for (int d = 1; d < 256; d <<= 1) {
        int x = (t >= d) ? sh[t - d] : 0;
        __syncthreads();
        sh[t] += x;
        __syncthreads();
    }
    if (i < NN) off[i] = sh[t] - v;
    if (t == 255) bsum[blockIdx.x] = sh[255];
}

__global__ __launch_bounds__(512) void k_scan2(int* __restrict__ bsum,
                                               int* __restrict__ boff) {
    __shared__ int sh[512];
    int t = threadIdx.x;
    int v = (t < NBLK) ? bsum[t] : 0;
    sh[t] = v;
    __syncthreads();
    for (int d = 1; d < 512; d <<= 1) {
        int x = (t >= d) ? sh[t - d] : 0;
        __syncthreads();
        sh[t] += x;
        __syncthreads();
    }
    if (t < NBLK) boff[t] = sh[t] - v;
}

__global__ __launch_bounds__(256) void k_scan3(const int* __restrict__ cnt,
                                               int* __restrict__ off,
                                               const int* __restrict__ boff,
                                               float* __restrict__ dinv,
                                               const int* __restrict__ batch,
                                               int* __restrict__ goff) {
    int i = blockIdx.x * 256 + threadIdx.x;
    if (i >= NN) return;
    off[i] += boff[i >> 8];
    dinv[i] = rsqrtf((float)cnt[i] + 1.0f);
    int b = batch[i];
    int bp = (i > 0) ? batch[i - 1] : -1;
    for (int g = bp + 1; g <= b; g++) goff[g] = i;
    if (i == NN - 1)
        for (int g = b + 1; g <= NG; g++) goff[g] = NN;
}

__global__ __launch_bounds__(256) void k_build(const int* __restrict__ src,
                                               const int* __restrict__ dst,
                                               const int* __restrict__ off,
                                               const int* __restrict__ slot,
                                               const float* __restrict__ dinv,
                                               float2* __restrict__ packed) {
    int e = blockIdx.x * 256 + threadIdx.x;
    int s = src[e];
    int d = dst[e];
    packed[off[d] + slot[e]] = make_float2(__int_as_float(s), dinv[s] * dinv[d]);
}

// ---------------- GEMM: H = X @ W ----------------
// No LDS. 256 threads = 32 node-groups(x4 nodes) x 8 col-groups(x12 cols).
// Register double-buffered k-chunks of 4: per chunk 384 VALU cyc of FMA hides
// the prefetched L2 loads (~200 cyc). X loads broadcast across the 8 cg lanes.
#define FMA12(XV, WAr, WBr, WCr, j)                                   \
    acc[j][0] += XV * WAr.x;  acc[j][1] += XV * WAr.y;                \
    acc[j][2] += XV * WAr.z;  acc[j][3] += XV * WAr.w;                \
    acc[j][4] += XV * WBr.x;  acc[j][5] += XV * WBr.y;                \
    acc[j][6] += XV * WBr.z;  acc[j][7] += XV * WBr.w;                \
    acc[j][8] += XV * WCr.x;  acc[j][9] += XV * WCr.y;                \
    acc[j][10] += XV * WCr.z; acc[j][11] += XV * WCr.w;

#define COMPUTE_CHUNK(XB, WA, WB, WC)                                              \
    {                                                                              \
        _Pragma("unroll") for (int j = 0; j < 4; j++) {                            \
            float xv = XB[j].x; FMA12(xv, WA[0], WB[0], WC[0], j)                  \
        }                                                                          \
        _Pragma("unroll") for (int j = 0; j < 4; j++) {                            \
            float xv = XB[j].y; FMA12(xv, WA[1], WB[1], WC[1], j)                  \
        }                                                                          \
        _Pragma("unroll") for (int j = 0; j < 4; j++) {                            \
            float xv = XB[j].z; FMA12(xv, WA[2], WB[2], WC[2], j)                  \
        }                                                                          \
        _Pragma("unroll") for (int j = 0; j < 4; j++) {                            \
            float xv = XB[j].w; FMA12(xv, WA[3], WB[3], WC[3], j)                  \
        }                                                                          \
    }

#define LOAD_CHUNK(XB, WA, WB, WC, c)                                              \
    {                                                                              \
        _Pragma("unroll") for (int j = 0; j < 4; j++)                              \
            XB[j] = X4[(size_t)nrow[j] * 24 + (c)];                                \
        _Pragma("unroll") for (int kk = 0; kk < 4; kk++) {                         \
            int kr = ((c) * 4 + kk) * 24 + cg3;                                    \
            WA[kk] = W4[kr + 0];                                                   \
            WB[kk] = W4[kr + 1];                                                   \
            WC[kk] = W4[kr + 2];                                                   \
        }                                                                          \
    }

__global__ __launch_bounds__(256) void k_gemm96(const float* __restrict__ X,
                                                const float* __restrict__ W,
                                                float* __restrict__ H) {
    const int tid = threadIdx.x;
    const int cg = tid & 7;        // col group: cols cg*12..+11
    const int ng = tid >> 3;       // node group: 4 nodes
    const int cg3 = cg * 3;
    const int nb = blockIdx.x * TM + ng * 4;

    int nrow[4];
#pragma unroll
    for (int j = 0; j < 4; j++) nrow[j] = min(nb + j, NN - 1);  // clamp loads

    const float4* X4 = reinterpret_cast<const float4*>(X);
    const float4* W4 = reinterpret_cast<const float4*>(W);

    float acc[4][12];
#pragma unroll
    for (int j = 0; j < 4; j++)
#pragma unroll
        for (int c = 0; c < 12; c++) acc[j][c] = 0.0f;

    float4 xA[4], wAA[4], wBA[4], wCA[4];
    float4 xB[4], wAB[4], wBB[4], wCB[4];

    LOAD_CHUNK(xA, wAA, wBA, wCA, 0)
    for (int c = 0; c < 24; c += 2) {
        LOAD_CHUNK(xB, wAB, wBB, wCB, c + 1)
        COMPUTE_CHUNK(xA, wAA, wBA, wCA)
        if (c + 2 < 24) LOAD_CHUNK(xA, wAA, wBA, wCA, c + 2)
        COMPUTE_CHUNK(xB, wAB, wBB, wCB)
    }

    const int c0 = cg * 12;
#pragma unroll
    for (int j = 0; j < 4; j++) {
        int n = nb + j;
        if (n < NN) {
            float4* hp = reinterpret_cast<float4*>(&H[(size_t)n * CH + c0]);
            hp[0] = make_float4(acc[j][0], acc[j][1], acc[j][2], acc[j][3]);
            hp[1] = make_float4(acc[j][4], acc[j][5], acc[j][6], acc[j][7]);
            hp[2] = make_float4(acc[j][8], acc[j][9], acc[j][10], acc[j][11]);
        }
    }
}

// ---------------- per-dst aggregation (no atomics) ----------------
// B[n] = (relu?)( H[n]*dinv[n]^2 + b + sum_e coef_e * H[src_e] )
template <bool RELU>
__global__ __launch_bounds__(256) void k_aggregate(const int* __restrict__ off,
                                                   const float2* __restrict__ packed,
                                                   const float* __restrict__ dinv,
                                                   const float* __restrict__ bias,
                                                   const float* __restrict__ H,
                                                   float* __restrict__ B) {
    int idx = blockIdx.x * 256 + threadIdx.x;  // NN*24 exact
    int n = idx / 24;
    int c4 = idx - n * 24;
    int e0 = off[n];
    int e1 = (n + 1 < NN) ? off[n + 1] : NE;

    const float4* H4 = reinterpret_cast<const float4*>(H);
    float di = dinv[n];
    float d2 = di * di;
    float4 h = H4[(size_t)n * 24 + c4];
    float4 bb = reinterpret_cast<const float4*>(bias)[c4];
    float4 acc = make_float4(h.x * d2 + bb.x, h.y * d2 + bb.y,
                             h.z * d2 + bb.z, h.w * d2 + bb.w);

    int e = e0;
    for (; e + 4 <= e1; e += 4) {
        float2 p0 = packed[e + 0];
        float2 p1 = packed[e + 1];
        float2 p2 = packed[e + 2];
        float2 p3 = packed[e + 3];
        float4 v0 = H4[(size_t)__float_as_int(p0.x) * 24 + c4];
        float4 v1 = H4[(size_t)__float_as_int(p1.x) * 24 + c4];
        float4 v2 = H4[(size_t)__float_as_int(p2.x) * 24 + c4];
        float4 v3 = H4[(size_t)__float_as_int(p3.x) * 24 + c4];
        acc.x += v0.x * p0.y + v1.x * p1.y + v2.x * p2.y + v3.x * p3.y;
        acc.y += v0.y * p0.y + v1.y * p1.y + v2.y * p2.y + v3.y * p3.y;
        acc.z += v0.z * p0.y + v1.z * p1.y + v2.z * p2.y + v3.z * p3.y;
        acc.w += v0.w * p0.y + v1.w * p1.y + v2.w * p2.y + v3.w * p3.y;
    }
    for (; e < e1; e++) {
        float2 pc = packed[e];
        float4 v = H4[(size_t)__float_as_int(pc.x) * 24 + c4];
        acc.x += v.x * pc.y; acc.y += v.y * pc.y;
        acc.z += v.z * pc.y; acc.w += v.w * pc.y;
    }
    if (RELU) {
        acc.x = fmaxf(acc.x, 0.0f); acc.y = fmaxf(acc.y, 0.0f);
        acc.z = fmaxf(acc.z, 0.0f); acc.w = fmaxf(acc.w, 0.0f);
    }
    reinterpret_cast<float4*>(B)[(size_t)n * 24 + c4] = acc;
}

// ---------------- fused pool + final linear ----------------
__global__ __launch_bounds__(384) void k_pool_linear(const int* __restrict__ goff,
                                                     const float* __restrict__ B,
                                                     const float* __restrict__ Wlin,
                                                     float* __restrict__ out) {
    __shared__ float4 sh[16][24];
    __shared__ float pooled[CH];
    int g = blockIdx.x;
    int t = threadIdx.x;
    int nl = t / 24;
    int c4 = t - nl * 24;
    int s = goff[g];
    int e = goff[g + 1];

    float4 acc = make_float4(0.f, 0.f, 0.f, 0.f);
    const float4* B4 = reinterpret_cast<const float4*>(B);
    for (int n = s + nl; n < e; n += 16) {
        float4 v = B4[(size_t)n * 24 + c4];
        acc.x += v.x; acc.y += v.y; acc.z += v.z; acc.w += v.w;
    }
    sh[nl][c4] = acc;
    __syncthreads();

    if (t < 24) {
        float4 r = make_float4(0.f, 0.f, 0.f, 0.f);
#pragma unroll
        for (int j = 0; j < 16; j++) {
            float4 v = sh[j][t];
            r.x += v.x; r.y += v.y; r.z += v.z; r.w += v.w;
        }
        float inv = 1.0f / fmaxf((float)(e - s), 1.0f);
        pooled[t * 4 + 0] = r.x * inv;
        pooled[t * 4 + 1] = r.y * inv;
        pooled[t * 4 + 2] = r.z * inv;
        pooled[t * 4 + 3] = r.w * inv;
    }
    __syncthreads();

    if (t < OC) {
        float a = 0.0f;
#pragma unroll 8
        for (int k = 0; k < CH; k++) a += pooled[k] * Wlin[k * OC + t];
        out[g * OC + t] = a;
    }
}

// ---------------- launch ----------------
extern "C" void kernel_launch(void* const* d_in, const int* in_sizes, int n_in,
                              void* d_out, int out_size, void* d_ws, size_t ws_size,
                              hipStream_t stream) {
    const float* x = (const float*)d_in[0];
    const int* ei = (const int*)d_in[1];
    const int* src = ei;
    const int* dst = ei + NE;
    const int* batch = (const int*)d_in[2];
    const float* W1 = (const float*)d_in[3];
    const float* b1 = (const float*)d_in[4];
    const float* W2 = (const float*)d_in[5];
    const float* b2 = (const float*)d_in[6];
    const float* W3 = (const float*)d_in[7];
    const float* b3 = (const float*)d_in[8];
    const float* Wlin = (const float*)d_in[9];
    float* out = (float*)d_out;

    char* ws = (char*)d_ws;
    float* H = (float*)ws;         ws += (size_t)NN * CH * 4;  // 38.4 MB
    float* B = (float*)ws;         ws += (size_t)NN * CH * 4;  // 38.4 MB
    float2* packed = (float2*)ws;  ws += (size_t)NE * 8;       // 6.4 MB
    float* dinv = (float*)ws;      ws += NN * 4;
    int* cnt = (int*)ws;           ws += NN * 4;
    int* off = (int*)ws;           ws += NN * 4;
    int* bsum = (int*)ws;          ws += 512 * 4;
    int* boff = (int*)ws;          ws += 512 * 4;
    int* goff = (int*)ws;          ws += (NG + 1) * 4;
    int* slot = (int*)B;  // B is dead until aggregate-1; reuse for edge slots

    // CSR by dst + dinv + graph offsets
    hipMemsetAsync(cnt, 0, NN * 4, stream);
    k_hist<<<NE / 256, 256, 0, stream>>>(dst, cnt, slot);
    k_scan1<<<NBLK, 256, 0, stream>>>(cnt, off, bsum);
    k_scan2<<<1, 512, 0, stream>>>(bsum, boff);
    k_scan3<<<NBLK, 256, 0, stream>>>(cnt, off, boff, dinv, batch, goff);
    k_build<<<NE / 256, 256, 0, stream>>>(src, dst, off, slot, dinv, packed);

    // layer 1: x -> H -> B (relu)
    k_gemm96<<<(NN + TM - 1) / TM, 256, 0, stream>>>(x, W1, H);
    k_aggregate<true><<<NN * 24 / 256, 256, 0, stream>>>(off, packed, dinv, b1, H, B);

    // layer 2: B -> H -> B (relu)
    k_gemm96<<<(NN + TM - 1) / TM, 256, 0, stream>>>(B, W2, H);
    k_aggregate<true><<<NN * 24 / 256, 256, 0, stream>>>(off, packed, dinv, b2, H, B);

    // layer 3: B -> H -> B (no relu)
    k_gemm96<<<(NN + TM - 1) / TM, 256, 0, stream>>>(B, W3, H);
    k_aggregate<false><<<NN * 24 / 256, 256, 0, stream>>>(off, packed, dinv, b3, H, B);

    // fused pool + linear
    k_pool_linear<<<NG, 384, 0, stream>>>(goff, B, Wlin, out);
}

// Round 6
// 366.356 us; speedup vs baseline: 1.3323x; 1.3323x over previous
//
#include <hip/hip_runtime.h>

#define NN 100000   // nodes
#define NE 800000   // edges  (NE % 256 == 0)
#define NG 256      // graphs
#define CH 96       // in/hidden channels
#define OC 16       // out channels
#define NBLK 391    // ceil(NN/256)
#define TM 128      // gemm node tile (8 row-tiles of 16)
#define WPAD 104    // Wt row stride in ushorts (16B-aligned, 2-way-conflict only)

typedef __attribute__((ext_vector_type(8))) short bf16x8;
typedef __attribute__((ext_vector_type(4))) float f32x4;

// ---------------- CSR build ----------------
__global__ __launch_bounds__(256) void k_hist(const int* __restrict__ dst,
                                              int* __restrict__ cnt,
                                              int* __restrict__ slot) {
    int e = blockIdx.x * 256 + threadIdx.x;
    slot[e] = atomicAdd(&cnt[dst[e]], 1);
}

__global__ __launch_bounds__(256) void k_scan1(const int* __restrict__ cnt,
                                               int* __restrict__ off,
                                               int* __restrict__ bsum) {
    __shared__ int sh[256];
    int t = threadIdx.x;
    int i = blockIdx.x * 256 + t;
    int v = (i < NN) ? cnt[i] : 0;
    sh[t] = v;
    __syncthreads();
    for (int d = 1; d < 256; d <<= 1) {
        int x = (t >= d) ? sh[t - d] : 0;
        __syncthreads();
        sh[t] += x;
        __syncthreads();
    }
    if (i < NN) off[i] = sh[t] - v;
    if (t == 255) bsum[blockIdx.x] = sh[255];
}

__global__ __launch_bounds__(512) void k_scan2(int* __restrict__ bsum,
                                               int* __restrict__ boff) {
    __shared__ int sh[512];
    int t = threadIdx.x;
    int v = (t < NBLK) ? bsum[t] : 0;
    sh[t] = v;
    __syncthreads();
    for (int d = 1; d < 512; d <<= 1) {
        int x = (t >= d) ? sh[t - d] : 0;
        __syncthreads();
        sh[t] += x;
        __syncthreads();
    }
    if (t < NBLK) boff[t] = sh[t] - v;
}

__global__ __launch_bounds__(256) void k_scan3(const int* __restrict__ cnt,
                                               int* __restrict__ off,
                                               const int* __restrict__ boff,
                                               float* __restrict__ dinv,
                                               const int* __restrict__ batch,
                                               int* __restrict__ goff) {
    int i = blockIdx.x * 256 + threadIdx.x;
    if (i >= NN) return;
    off[i] += boff[i >> 8];
    dinv[i] = rsqrtf((float)cnt[i] + 1.0f);
    int b = batch[i];
    int bp = (i > 0) ? batch[i - 1] : -1;
    for (int g = bp + 1; g <= b; g++) goff[g] = i;
    if (i == NN - 1)
        for (int g = b + 1; g <= NG; g++) goff[g] = NN;
}

__global__ __launch_bounds__(256) void k_build(const int* __restrict__ src,
                                               const int* __restrict__ dst,
                                               const int* __restrict__ off,
                                               const int* __restrict__ slot,
                                               const float* __restrict__ dinv,
                                               float2* __restrict__ packed) {
    int e = blockIdx.x * 256 + threadIdx.x;
    int s = src[e];
    int d = dst[e];
    packed[off[d] + slot[e]] = make_float2(__int_as_float(s), dinv[s] * dinv[d]);
}

// ---------------- MFMA GEMM: H = X @ W (fp32 in/out, split-bf16 internally) ----
__device__ __forceinline__ unsigned short f2bf(float x) {
    unsigned u = __float_as_uint(x);
    return (unsigned short)((u + 0x7fffu + ((u >> 16) & 1u)) >> 16);  // RNE
}
__device__ __forceinline__ float bf2f(unsigned short h) {
    return __uint_as_float(((unsigned)h) << 16);
}

// Per-lane A fragment: 8 consecutive fp32 -> hi/lo bf16x8
__device__ __forceinline__ void split8(const float4 a, const float4 b,
                                       bf16x8& hi, bf16x8& lo) {
    float v[8] = {a.x, a.y, a.z, a.w, b.x, b.y, b.z, b.w};
#pragma unroll
    for (int j = 0; j < 8; j++) {
        unsigned short h = f2bf(v[j]);
        hi[j] = (short)h;
        lo[j] = (short)f2bf(v[j] - bf2f(h));
    }
}

// 256 threads = 4 waves; wave w owns row-tiles {2w,2w+1} x 6 col-tiles.
// MFMA 16x16x32_bf16: A[m=lane&15][k=quad*8+j], B[k=quad*8+j][n=lane&15],
// C/D: col=lane&15, row=quad*4+reg.
__global__ __launch_bounds__(256) void k_gemm96(const float* __restrict__ X,
                                                const float* __restrict__ W,
                                                float* __restrict__ H) {
    __shared__ unsigned short WtHi[CH * WPAD];  // Wt[n][k] bf16 hi
    __shared__ unsigned short WtLo[CH * WPAD];  // Wt[n][k] bf16 lo

    const int tid = threadIdx.x;
    const int n0 = blockIdx.x * TM;

    // ---- stage W (96x96 fp32, row-major [k][n]) -> transposed bf16 hi/lo ----
    {
        const float4* W4 = reinterpret_cast<const float4*>(W);
#pragma unroll
        for (int i = 0; i < 9; i++) {  // 256*9 = 2304 float4 = 9216 floats
            int f4 = tid * 9 + i;
            int k = f4 / 24;
            int nn = (f4 - k * 24) * 4;
            float4 v = W4[f4];
            float vv[4] = {v.x, v.y, v.z, v.w};
#pragma unroll
            for (int e = 0; e < 4; e++) {
                unsigned short h = f2bf(vv[e]);
                WtHi[(nn + e) * WPAD + k] = h;
                WtLo[(nn + e) * WPAD + k] = f2bf(vv[e] - bf2f(h));
            }
        }
    }
    __syncthreads();

    const int lane = tid & 63;
    const int wave = tid >> 6;
    const int lrow = lane & 15;   // row within tile (A), col within tile (B, C/D)
    const int quad = lane >> 4;   // 0..3

    const float4* X4 = reinterpret_cast<const float4*>(X);

    f32x4 acc[2][6];
#pragma unroll
    for (int rt = 0; rt < 2; rt++)
#pragma unroll
        for (int ct = 0; ct < 6; ct++) acc[rt][ct] = (f32x4){0.f, 0.f, 0.f, 0.f};

    int arow[2];
#pragma unroll
    for (int rt = 0; rt < 2; rt++)
        arow[rt] = min(n0 + (wave * 2 + rt) * 16 + lrow, NN - 1);

#pragma unroll
    for (int kc = 0; kc < 3; kc++) {
        // A fragments (global, fp32 -> split bf16)
        bf16x8 ahi[2], alo[2];
#pragma unroll
        for (int rt = 0; rt < 2; rt++) {
            int fo = (arow[rt] * CH + kc * 32 + quad * 8) >> 2;  // float4 index
            split8(X4[fo], X4[fo + 1], ahi[rt], alo[rt]);
        }
        // B fragments (LDS) + MFMA
#pragma unroll
        for (int ct = 0; ct < 6; ct++) {
            int bo = (ct * 16 + lrow) * WPAD + kc * 32 + quad * 8;
            bf16x8 bhi = *reinterpret_cast<const bf16x8*>(&WtHi[bo]);
            bf16x8 blo = *reinterpret_cast<const bf16x8*>(&WtLo[bo]);
#pragma unroll
            for (int rt = 0; rt < 2; rt++) {
                acc[rt][ct] = __builtin_amdgcn_mfma_f32_16x16x32_bf16(
                    alo[rt], bhi, acc[rt][ct], 0, 0, 0);
                acc[rt][ct] = __builtin_amdgcn_mfma_f32_16x16x32_bf16(
                    ahi[rt], blo, acc[rt][ct], 0, 0, 0);
                acc[rt][ct] = __builtin_amdgcn_mfma_f32_16x16x32_bf16(
                    ahi[rt], bhi, acc[rt][ct], 0, 0, 0);
            }
        }
    }

    // ---- store C/D: row = tile0 + quad*4 + reg, col = ct*16 + lrow ----
#pragma unroll
    for (int rt = 0; rt < 2; rt++) {
        int rbase = n0 + (wave * 2 + rt) * 16 + quad * 4;
#pragma unroll
        for (int ct = 0; ct < 6; ct++) {
            int col = ct * 16 + lrow;
#pragma unroll
            for (int r = 0; r < 4; r++) {
                int row = rbase + r;
                if (row < NN) H[(size_t)row * CH + col] = acc[rt][ct][r];
            }
        }
    }
}

// ---------------- per-dst aggregation (no atomics) ----------------
// B[n] = (relu?)( H[n]*dinv[n]^2 + b + sum_e coef_e * H[src_e] )
template <bool RELU>
__global__ __launch_bounds__(256) void k_aggregate(const int* __restrict__ off,
                                                   const float2* __restrict__ packed,
                                                   const float* __restrict__ dinv,
                                                   const float* __restrict__ bias,
                                                   const float* __restrict__ H,
                                                   float* __restrict__ B) {
    int idx = blockIdx.x * 256 + threadIdx.x;  // NN*24 exact
    int n = idx / 24;
    int c4 = idx - n * 24;
    int e0 = off[n];
    int e1 = (n + 1 < NN) ? off[n + 1] : NE;

    const float4* H4 = reinterpret_cast<const float4*>(H);
    float di = dinv[n];
    float d2 = di * di;
    float4 h = H4[(size_t)n * 24 + c4];
    float4 bb = reinterpret_cast<const float4*>(bias)[c4];
    float4 acc = make_float4(h.x * d2 + bb.x, h.y * d2 + bb.y,
                             h.z * d2 + bb.z, h.w * d2 + bb.w);

    int e = e0;
    for (; e + 4 <= e1; e += 4) {
        float2 p0 = packed[e + 0];
        float2 p1 = packed[e + 1];
        float2 p2 = packed[e + 2];
        float2 p3 = packed[e + 3];
        float4 v0 = H4[(size_t)__float_as_int(p0.x) * 24 + c4];
        float4 v1 = H4[(size_t)__float_as_int(p1.x) * 24 + c4];
        float4 v2 = H4[(size_t)__float_as_int(p2.x) * 24 + c4];
        float4 v3 = H4[(size_t)__float_as_int(p3.x) * 24 + c4];
        acc.x += v0.x * p0.y + v1.x * p1.y + v2.x * p2.y + v3.x * p3.y;
        acc.y += v0.y * p0.y + v1.y * p1.y + v2.y * p2.y + v3.y * p3.y;
        acc.z += v0.z * p0.y + v1.z * p1.y + v2.z * p2.y + v3.z * p3.y;
        acc.w += v0.w * p0.y + v1.w * p1.y + v2.w * p2.y + v3.w * p3.y;
    }
    for (; e < e1; e++) {
        float2 pc = packed[e];
        float4 v = H4[(size_t)__float_as_int(pc.x) * 24 + c4];
        acc.x += v.x * pc.y; acc.y += v.y * pc.y;
        acc.z += v.z * pc.y; acc.w += v.w * pc.y;
    }
    if (RELU) {
        acc.x = fmaxf(acc.x, 0.0f); acc.y = fmaxf(acc.y, 0.0f);
        acc.z = fmaxf(acc.z, 0.0f); acc.w = fmaxf(acc.w, 0.0f);
    }
    reinterpret_cast<float4*>(B)[(size_t)n * 24 + c4] = acc;
}

// ---------------- fused pool + final linear ----------------
__global__ __launch_bounds__(384) void k_pool_linear(const int* __restrict__ goff,
                                                     const float* __restrict__ B,
                                                     const float* __restrict__ Wlin,
                                                     float* __restrict__ out) {
    __shared__ float4 sh[16][24];
    __shared__ float pooled[CH];
    int g = blockIdx.x;
    int t = threadIdx.x;
    int nl = t / 24;
    int c4 = t - nl * 24;
    int s = goff[g];
    int e = goff[g + 1];

    float4 acc = make_float4(0.f, 0.f, 0.f, 0.f);
    const float4* B4 = reinterpret_cast<const float4*>(B);
    for (int n = s + nl; n < e; n += 16) {
        float4 v = B4[(size_t)n * 24 + c4];
        acc.x += v.x; acc.y += v.y; acc.z += v.z; acc.w += v.w;
    }
    sh[nl][c4] = acc;
    __syncthreads();

    if (t < 24) {
        float4 r = make_float4(0.f, 0.f, 0.f, 0.f);
#pragma unroll
        for (int j = 0; j < 16; j++) {
            float4 v = sh[j][t];
            r.x += v.x; r.y += v.y; r.z += v.z; r.w += v.w;
        }
        float inv = 1.0f / fmaxf((float)(e - s), 1.0f);
        pooled[t * 4 + 0] = r.x * inv;
        pooled[t * 4 + 1] = r.y * inv;
        pooled[t * 4 + 2] = r.z * inv;
        pooled[t * 4 + 3] = r.w * inv;
    }
    __syncthreads();

    if (t < OC) {
        float a = 0.0f;
#pragma unroll 8
        for (int k = 0; k < CH; k++) a += pooled[k] * Wlin[k * OC + t];
        out[g * OC + t] = a;
    }
}

// ---------------- launch ----------------
extern "C" void kernel_launch(void* const* d_in, const int* in_sizes, int n_in,
                              void* d_out, int out_size, void* d_ws, size_t ws_size,
                              hipStream_t stream) {
    const float* x = (const float*)d_in[0];
    const int* ei = (const int*)d_in[1];
    const int* src = ei;
    const int* dst = ei + NE;
    const int* batch = (const int*)d_in[2];
    const float* W1 = (const float*)d_in[3];
    const float* b1 = (const float*)d_in[4];
    const float* W2 = (const float*)d_in[5];
    const float* b2 = (const float*)d_in[6];
    const float* W3 = (const float*)d_in[7];
    const float* b3 = (const float*)d_in[8];
    const float* Wlin = (const float*)d_in[9];
    float* out = (float*)d_out;

    char* ws = (char*)d_ws;
    float* H = (float*)ws;         ws += (size_t)NN * CH * 4;  // 38.4 MB
    float* B = (float*)ws;         ws += (size_t)NN * CH * 4;  // 38.4 MB
    float2* packed = (float2*)ws;  ws += (size_t)NE * 8;       // 6.4 MB
    float* dinv = (float*)ws;      ws += NN * 4;
    int* cnt = (int*)ws;           ws += NN * 4;
    int* off = (int*)ws;           ws += NN * 4;
    int* bsum = (int*)ws;          ws += 512 * 4;
    int* boff = (int*)ws;          ws += 512 * 4;
    int* goff = (int*)ws;          ws += (NG + 1) * 4;
    int* slot = (int*)B;  // B is dead until aggregate-1; reuse for edge slots

    // CSR by dst + dinv + graph offsets
    hipMemsetAsync(cnt, 0, NN * 4, stream);
    k_hist<<<NE / 256, 256, 0, stream>>>(dst, cnt, slot);
    k_scan1<<<NBLK, 256, 0, stream>>>(cnt, off, bsum);
    k_scan2<<<1, 512, 0, stream>>>(bsum, boff);
    k_scan3<<<NBLK, 256, 0, stream>>>(cnt, off, boff, dinv, batch, goff);
    k_build<<<NE / 256, 256, 0, stream>>>(src, dst, off, slot, dinv, packed);

    const int gblk = (NN + TM - 1) / TM;

    // layer 1: x -> H -> B (relu)
    k_gemm96<<<gblk, 256, 0, stream>>>(x, W1, H);
    k_aggregate<true><<<NN * 24 / 256, 256, 0, stream>>>(off, packed, dinv, b1, H, B);

    // layer 2: B -> H -> B (relu)
    k_gemm96<<<gblk, 256, 0, stream>>>(B, W2, H);
    k_aggregate<true><<<NN * 24 / 256, 256, 0, stream>>>(off, packed, dinv, b2, H, B);

    // layer 3: B -> H -> B (no relu)
    k_gemm96<<<gblk, 256, 0, stream>>>(B, W3, H);
    k_aggregate<false><<<NN * 24 / 256, 256, 0, stream>>>(off, packed, dinv, b3, H, B);

    // fused pool + linear
    k_pool_linear<<<NG, 384, 0, stream>>>(goff, B, Wlin, out);
}

// Round 7
// 321.590 us; speedup vs baseline: 1.5177x; 1.1392x over previous
//
#include <hip/hip_runtime.h>

#define NN 100000   // nodes
#define NE 800000   // edges  (NE % 256 == 0)
#define NG 256      // graphs
#define CH 96       // in/hidden channels
#define OC 16       // out channels
#define NBLK 391    // ceil(NN/256)
#define TM 128      // gemm node tile (8 row-tiles of 16)
#define WPAD 104    // Wt row stride in ushorts

typedef __attribute__((ext_vector_type(8))) short bf16x8;
typedef __attribute__((ext_vector_type(4))) float f32x4;

// ---------------- CSR build ----------------
__global__ __launch_bounds__(256) void k_hist(const int* __restrict__ dst,
                                              int* __restrict__ cnt,
                                              int* __restrict__ slot) {
    int e = blockIdx.x * 256 + threadIdx.x;
    slot[e] = atomicAdd(&cnt[dst[e]], 1);
}

__global__ __launch_bounds__(256) void k_scan1(const int* __restrict__ cnt,
                                               int* __restrict__ off,
                                               int* __restrict__ bsum) {
    __shared__ int sh[256];
    int t = threadIdx.x;
    int i = blockIdx.x * 256 + t;
    int v = (i < NN) ? cnt[i] : 0;
    sh[t] = v;
    __syncthreads();
    for (int d = 1; d < 256; d <<= 1) {
        int x = (t >= d) ? sh[t - d] : 0;
        __syncthreads();
        sh[t] += x;
        __syncthreads();
    }
    if (i < NN) off[i] = sh[t] - v;
    if (t == 255) bsum[blockIdx.x] = sh[255];
}

__global__ __launch_bounds__(512) void k_scan2(int* __restrict__ bsum,
                                               int* __restrict__ boff) {
    __shared__ int sh[512];
    int t = threadIdx.x;
    int v = (t < NBLK) ? bsum[t] : 0;
    sh[t] = v;
    __syncthreads();
    for (int d = 1; d < 512; d <<= 1) {
        int x = (t >= d) ? sh[t - d] : 0;
        __syncthreads();
        sh[t] += x;
        __syncthreads();
    }
    if (t < NBLK) boff[t] = sh[t] - v;
}

__global__ __launch_bounds__(256) void k_scan3(const int* __restrict__ cnt,
                                               int* __restrict__ off,
                                               const int* __restrict__ boff,
                                               float* __restrict__ dinv,
                                               const int* __restrict__ batch,
                                               int* __restrict__ goff) {
    int i = blockIdx.x * 256 + threadIdx.x;
    if (i >= NN) return;
    off[i] += boff[i >> 8];
    dinv[i] = rsqrtf((float)cnt[i] + 1.0f);
    int b = batch[i];
    int bp = (i > 0) ? batch[i - 1] : -1;
    for (int g = bp + 1; g <= b; g++) goff[g] = i;
    if (i == NN - 1)
        for (int g = b + 1; g <= NG; g++) goff[g] = NN;
}

__global__ __launch_bounds__(256) void k_build(const int* __restrict__ src,
                                               const int* __restrict__ dst,
                                               const int* __restrict__ off,
                                               const int* __restrict__ slot,
                                               const float* __restrict__ dinv,
                                               float2* __restrict__ packed) {
    int e = blockIdx.x * 256 + threadIdx.x;
    int s = src[e];
    int d = dst[e];
    packed[off[d] + slot[e]] = make_float2(__int_as_float(s), dinv[s] * dinv[d]);
}

// ---------------- MFMA GEMM: H(bf16) = X(fp32) @ W, split-bf16 internally ----
__device__ __forceinline__ unsigned short f2bf(float x) {
    unsigned u = __float_as_uint(x);
    return (unsigned short)((u + 0x7fffu + ((u >> 16) & 1u)) >> 16);  // RNE
}
__device__ __forceinline__ float bf2f(unsigned short h) {
    return __uint_as_float(((unsigned)h) << 16);
}

__device__ __forceinline__ void split8(const float4 a, const float4 b,
                                       bf16x8& hi, bf16x8& lo) {
    float v[8] = {a.x, a.y, a.z, a.w, b.x, b.y, b.z, b.w};
#pragma unroll
    for (int j = 0; j < 8; j++) {
        unsigned short h = f2bf(v[j]);
        hi[j] = (short)h;
        lo[j] = (short)f2bf(v[j] - bf2f(h));
    }
}

// 256 threads = 4 waves; wave w owns row-tiles {2w,2w+1} x 6 col-tiles.
__global__ __launch_bounds__(256) void k_gemm96(const float* __restrict__ X,
                                                const float* __restrict__ W,
                                                unsigned short* __restrict__ H) {
    __shared__ unsigned short WtHi[CH * WPAD];
    __shared__ unsigned short WtLo[CH * WPAD];

    const int tid = threadIdx.x;
    const int n0 = blockIdx.x * TM;

    {
        const float4* W4 = reinterpret_cast<const float4*>(W);
#pragma unroll
        for (int i = 0; i < 9; i++) {
            int f4 = tid * 9 + i;
            int k = f4 / 24;
            int nn = (f4 - k * 24) * 4;
            float4 v = W4[f4];
            float vv[4] = {v.x, v.y, v.z, v.w};
#pragma unroll
            for (int e = 0; e < 4; e++) {
                unsigned short h = f2bf(vv[e]);
                WtHi[(nn + e) * WPAD + k] = h;
                WtLo[(nn + e) * WPAD + k] = f2bf(vv[e] - bf2f(h));
            }
        }
    }
    __syncthreads();

    const int lane = tid & 63;
    const int wave = tid >> 6;
    const int lrow = lane & 15;
    const int quad = lane >> 4;

    const float4* X4 = reinterpret_cast<const float4*>(X);

    f32x4 acc[2][6];
#pragma unroll
    for (int rt = 0; rt < 2; rt++)
#pragma unroll
        for (int ct = 0; ct < 6; ct++) acc[rt][ct] = (f32x4){0.f, 0.f, 0.f, 0.f};

    int arow[2];
#pragma unroll
    for (int rt = 0; rt < 2; rt++)
        arow[rt] = min(n0 + (wave * 2 + rt) * 16 + lrow, NN - 1);

#pragma unroll
    for (int kc = 0; kc < 3; kc++) {
        bf16x8 ahi[2], alo[2];
#pragma unroll
        for (int rt = 0; rt < 2; rt++) {
            int fo = (arow[rt] * CH + kc * 32 + quad * 8) >> 2;
            split8(X4[fo], X4[fo + 1], ahi[rt], alo[rt]);
        }
#pragma unroll
        for (int ct = 0; ct < 6; ct++) {
            int bo = (ct * 16 + lrow) * WPAD + kc * 32 + quad * 8;
            bf16x8 bhi = *reinterpret_cast<const bf16x8*>(&WtHi[bo]);
            bf16x8 blo = *reinterpret_cast<const bf16x8*>(&WtLo[bo]);
#pragma unroll
            for (int rt = 0; rt < 2; rt++) {
                acc[rt][ct] = __builtin_amdgcn_mfma_f32_16x16x32_bf16(
                    alo[rt], bhi, acc[rt][ct], 0, 0, 0);
                acc[rt][ct] = __builtin_amdgcn_mfma_f32_16x16x32_bf16(
                    ahi[rt], blo, acc[rt][ct], 0, 0, 0);
                acc[rt][ct] = __builtin_amdgcn_mfma_f32_16x16x32_bf16(
                    ahi[rt], bhi, acc[rt][ct], 0, 0, 0);
            }
        }
    }

    // store C/D as bf16: row = base + quad*4 + r, col = ct*16 + lrow
#pragma unroll
    for (int rt = 0; rt < 2; rt++) {
        int rbase = n0 + (wave * 2 + rt) * 16 + quad * 4;
#pragma unroll
        for (int ct = 0; ct < 6; ct++) {
            int col = ct * 16 + lrow;
#pragma unroll
            for (int r = 0; r < 4; r++) {
                int row = rbase + r;
                if (row < NN) H[(size_t)row * CH + col] = f2bf(acc[rt][ct][r]);
            }
        }
    }
}

// ---------------- per-dst aggregation (no atomics, bf16 gathers) ----------------
// B[n] = (relu?)( H[n]*dinv[n]^2 + b + sum_e coef_e * H[src_e] )
__device__ __forceinline__ float4 us4_to_f4(ushort4 u) {
    return make_float4(bf2f(u.x), bf2f(u.y), bf2f(u.z), bf2f(u.w));
}

template <bool RELU>
__global__ __launch_bounds__(256) void k_aggregate(const int* __restrict__ off,
                                                   const float2* __restrict__ packed,
                                                   const float* __restrict__ dinv,
                                                   const float* __restrict__ bias,
                                                   const unsigned short* __restrict__ H,
                                                   float* __restrict__ B) {
    int idx = blockIdx.x * 256 + threadIdx.x;  // NN*24 exact
    int n = idx / 24;
    int c4 = idx - n * 24;
    int e0 = off[n];
    int e1 = (n + 1 < NN) ? off[n + 1] : NE;

    const ushort4* H4 = reinterpret_cast<const ushort4*>(H);
    float di = dinv[n];
    float d2 = di * di;
    float4 h = us4_to_f4(H4[(size_t)n * 24 + c4]);
    float4 bb = reinterpret_cast<const float4*>(bias)[c4];
    float4 acc = make_float4(h.x * d2 + bb.x, h.y * d2 + bb.y,
                             h.z * d2 + bb.z, h.w * d2 + bb.w);

    int e = e0;
    for (; e + 4 <= e1; e += 4) {
        float2 p0 = packed[e + 0];
        float2 p1 = packed[e + 1];
        float2 p2 = packed[e + 2];
        float2 p3 = packed[e + 3];
        float4 v0 = us4_to_f4(H4[(size_t)__float_as_int(p0.x) * 24 + c4]);
        float4 v1 = us4_to_f4(H4[(size_t)__float_as_int(p1.x) * 24 + c4]);
        float4 v2 = us4_to_f4(H4[(size_t)__float_as_int(p2.x) * 24 + c4]);
        float4 v3 = us4_to_f4(H4[(size_t)__float_as_int(p3.x) * 24 + c4]);
        acc.x += v0.x * p0.y + v1.x * p1.y + v2.x * p2.y + v3.x * p3.y;
        acc.y += v0.y * p0.y + v1.y * p1.y + v2.y * p2.y + v3.y * p3.y;
        acc.z += v0.z * p0.y + v1.z * p1.y + v2.z * p2.y + v3.z * p3.y;
        acc.w += v0.w * p0.y + v1.w * p1.y + v2.w * p2.y + v3.w * p3.y;
    }
    for (; e < e1; e++) {
        float2 pc = packed[e];
        float4 v = us4_to_f4(H4[(size_t)__float_as_int(pc.x) * 24 + c4]);
        acc.x += v.x * pc.y; acc.y += v.y * pc.y;
        acc.z += v.z * pc.y; acc.w += v.w * pc.y;
    }
    if (RELU) {
        acc.x = fmaxf(acc.x, 0.0f); acc.y = fmaxf(acc.y, 0.0f);
        acc.z = fmaxf(acc.z, 0.0f); acc.w = fmaxf(acc.w, 0.0f);
    }
    reinterpret_cast<float4*>(B)[(size_t)n * 24 + c4] = acc;
}

// ---------------- fused pool + final linear ----------------
__global__ __launch_bounds__(384) void k_pool_linear(const int* __restrict__ goff,
                                                     const float* __restrict__ B,
                                                     const float* __restrict__ Wlin,
                                                     float* __restrict__ out) {
    __shared__ float4 sh[16][24];
    __shared__ float pooled[CH];
    int g = blockIdx.x;
    int t = threadIdx.x;
    int nl = t / 24;
    int c4 = t - nl * 24;
    int s = goff[g];
    int e = goff[g + 1];

    float4 acc = make_float4(0.f, 0.f, 0.f, 0.f);
    const float4* B4 = reinterpret_cast<const float4*>(B);
    for (int n = s + nl; n < e; n += 16) {
        float4 v = B4[(size_t)n * 24 + c4];
        acc.x += v.x; acc.y += v.y; acc.z += v.z; acc.w += v.w;
    }
    sh[nl][c4] = acc;
    __syncthreads();

    if (t < 24) {
        float4 r = make_float4(0.f, 0.f, 0.f, 0.f);
#pragma unroll
        for (int j = 0; j < 16; j++) {
            float4 v = sh[j][t];
            r.x += v.x; r.y += v.y; r.z += v.z; r.w += v.w;
        }
        float inv = 1.0f / fmaxf((float)(e - s), 1.0f);
        pooled[t * 4 + 0] = r.x * inv;
        pooled[t * 4 + 1] = r.y * inv;
        pooled[t * 4 + 2] = r.z * inv;
        pooled[t * 4 + 3] = r.w * inv;
    }
    __syncthreads();

    if (t < OC) {
        float a = 0.0f;
#pragma unroll 8
        for (int k = 0; k < CH; k++) a += pooled[k] * Wlin[k * OC + t];
        out[g * OC + t] = a;
    }
}

// ---------------- launch ----------------
extern "C" void kernel_launch(void* const* d_in, const int* in_sizes, int n_in,
                              void* d_out, int out_size, void* d_ws, size_t ws_size,
                              hipStream_t stream) {
    const float* x = (const float*)d_in[0];
    const int* ei = (const int*)d_in[1];
    const int* src = ei;
    const int* dst = ei + NE;
    const int* batch = (const int*)d_in[2];
    const float* W1 = (const float*)d_in[3];
    const float* b1 = (const float*)d_in[4];
    const float* W2 = (const float*)d_in[5];
    const float* b2 = (const float*)d_in[6];
    const float* W3 = (const float*)d_in[7];
    const float* b3 = (const float*)d_in[8];
    const float* Wlin = (const float*)d_in[9];
    float* out = (float*)d_out;

    char* ws = (char*)d_ws;
    unsigned short* H = (unsigned short*)ws;  ws += (size_t)NN * CH * 2;  // 19.2 MB
    float* B = (float*)ws;         ws += (size_t)NN * CH * 4;  // 38.4 MB
    float2* packed = (float2*)ws;  ws += (size_t)NE * 8;       // 6.4 MB
    float* dinv = (float*)ws;      ws += NN * 4;
    int* cnt = (int*)ws;           ws += NN * 4;
    int* off = (int*)ws;           ws += NN * 4;
    int* bsum = (int*)ws;          ws += 512 * 4;
    int* boff = (int*)ws;          ws += 512 * 4;
    int* goff = (int*)ws;          ws += (NG + 1) * 4;
    int* slot = (int*)B;  // B is dead until aggregate-1; reuse for edge slots

    // CSR by dst + dinv + graph offsets
    hipMemsetAsync(cnt, 0, NN * 4, stream);
    k_hist<<<NE / 256, 256, 0, stream>>>(dst, cnt, slot);
    k_scan1<<<NBLK, 256, 0, stream>>>(cnt, off, bsum);
    k_scan2<<<1, 512, 0, stream>>>(bsum, boff);
    k_scan3<<<NBLK, 256, 0, stream>>>(cnt, off, boff, dinv, batch, goff);
    k_build<<<NE / 256, 256, 0, stream>>>(src, dst, off, slot, dinv, packed);

    const int gblk = (NN + TM - 1) / TM;

    // layer 1: x -> H -> B (relu)
    k_gemm96<<<gblk, 256, 0, stream>>>(x, W1, H);
    k_aggregate<true><<<NN * 24 / 256, 256, 0, stream>>>(off, packed, dinv, b1, H, B);

    // layer 2: B -> H -> B (relu)
    k_gemm96<<<gblk, 256, 0, stream>>>(B, W2, H);
    k_aggregate<true><<<NN * 24 / 256, 256, 0, stream>>>(off, packed, dinv, b2, H, B);

    // layer 3: B -> H -> B (no relu)
    k_gemm96<<<gblk, 256, 0, stream>>>(B, W3, H);
    k_aggregate<false><<<NN * 24 / 256, 256, 0, stream>>>(off, packed, dinv, b3, H, B);

    // fused pool + linear
    k_pool_linear<<<NG, 384, 0, stream>>>(goff, B, Wlin, out);
}